// Round 7
// baseline (452.478 us; speedup 1.0000x reference)
//
#include <hip/hip_runtime.h>
#include <hip/hip_bf16.h>

#define BATCH 8
#define CIN 32
#define COUT 32
#define NK 4
#define HH 512
#define WW 512
#define HW (HH*WW)
#define EPSV 1e-8f

typedef __attribute__((ext_vector_type(8))) short short8;   // bf16 MFMA frag (4 VGPR)
typedef __attribute__((ext_vector_type(16))) float f32x16;  // 32x32 accumulator

static __device__ __forceinline__ unsigned short to_bf16(float f) {
    __hip_bfloat16 h = __float2bfloat16(f);
    return *reinterpret_cast<unsigned short*>(&h);
}
static __device__ __forceinline__ unsigned int pack2(float a, float b) {
    return (unsigned int)to_bf16(a) | ((unsigned int)to_bf16(b) << 16);
}

// ---------------------------------------------------------------------------
// Kernel 1: mixed+modulated+demodulated weights -> bf16 wt[b][oc][k], k=tap*32+ci
// ---------------------------------------------------------------------------
__global__ __launch_bounds__(320) void prep_weights(
    const float* __restrict__ mod,         // [B, CIN]
    const float* __restrict__ kernel_mod,  // [B, NK]
    const float* __restrict__ weights,     // [NK, COUT, CIN, 3, 3]
    unsigned short* __restrict__ wtb)      // [B, COUT, 288] bf16
{
    const int b  = blockIdx.x / COUT;
    const int oc = blockIdx.x % COUT;
    const int t  = threadIdx.x;            // 0..319, active < 288

    const float k0 = kernel_mod[b * NK + 0];
    const float k1 = kernel_mod[b * NK + 1];
    const float k2 = kernel_mod[b * NK + 2];
    const float k3 = kernel_mod[b * NK + 3];
    const float mx = fmaxf(fmaxf(k0, k1), fmaxf(k2, k3));
    const float e0 = expf(k0 - mx), e1 = expf(k1 - mx);
    const float e2 = expf(k2 - mx), e3 = expf(k3 - mx);
    const float inv_s = 1.0f / (e0 + e1 + e2 + e3);
    const float a0 = e0 * inv_s, a1 = e1 * inv_s, a2 = e2 * inv_s, a3 = e3 * inv_s;

    float w = 0.0f;
    int i = 0, tap = 0;
    if (t < CIN * 9) {
        i   = t / 9;
        tap = t % 9;
        const int base = (oc * CIN + i) * 9 + tap;
        const int nstride = COUT * CIN * 9;
        w = a0 * weights[base]
          + a1 * weights[base + nstride]
          + a2 * weights[base + 2 * nstride]
          + a3 * weights[base + 3 * nstride];
        w *= (mod[b * CIN + i] + 1.0f);
    }

    float s = w * w;
    #pragma unroll
    for (int off = 1; off < 64; off <<= 1) s += __shfl_xor(s, off);
    __shared__ float red[5];
    const int wid = t >> 6, lane = t & 63;
    if (lane == 0) red[wid] = s;
    __syncthreads();
    const float tot = red[0] + red[1] + red[2] + red[3] + red[4];
    const float inv_norm = rsqrtf(fmaxf(tot, EPSV));

    if (t < CIN * 9)
        wtb[(b * COUT + oc) * 288 + tap * CIN + i] = to_bf16(w * inv_norm);
}

// ---------------------------------------------------------------------------
// Kernel 2 (fused v4): implicit-GEMM conv from f32 NCHW fmap.
// Block: 512 thr (8 waves), tile 16 rows x 32 px, one batch slice.
// Staging: thread owns a ci-PAIR (P = tid bits 3..6) and quads
// q = (tid&7) + 8*(tid>>7) + 32j. Loads 2 x float4 (two channel planes),
// writes 4 merged ds_write_b32 (pack bf16 lo/hi) -> per-instr 2-way max
// (8 consecutive stride-4 slots hit all 8 bank groups under swz; P&3 gives
// the dword offset; P vs P+4 differ only by chunk, bank-identical).
// Depth-2 load pipeline with NAMED register sets (no arrays -> no spill).
// Swizzle swz(s)=s^((s>>3)&7): bijection on [0,672).
// Slot xi in [0,36]: gx = x0 + xi - 1 (halo at xi=0).
// Compute: wave w -> row-tiles (w, w+8); 18 x mfma_f32_32x32x16_bf16 each.
// ---------------------------------------------------------------------------
#define ROWS 16
#define XW 32
#define SR 18              // staged rows
#define SPR 37             // slots per row (xi = 0..36 <-> gx = x0-1..x0+35)
#define CH_STRIDE 672      // > max swz image (671)

static __device__ __forceinline__ int swz(int s) {
    return s ^ ((s >> 3) & 7);     // bijection on [0, 672)
}

__global__ __launch_bounds__(512, 6) void conv_fused(
    const float* __restrict__ fmap,           // [B, CIN, H, W] f32
    const unsigned short* __restrict__ wtb,   // [B, COUT, 288] bf16
    float* __restrict__ out)                  // [B, COUT, H, W] f32
{
    __shared__ short8 lds[4 * CH_STRIDE];     // 43,008 B -> 3 blocks/CU

    // XCD-pinned decomposition: XCD (n&7) owns batch b, sweeps tiles row-major
    const int n  = blockIdx.x;
    const int b  = n & 7;
    const int m  = n >> 3;
    const int x0 = (m & 15) * XW;             // 16 x-tiles
    const int y0 = (m >> 4) * ROWS;           // 32 y-tiles

    const int t    = threadIdx.x;
    const int lane = t & 63;
    const int w    = t >> 6;                  // wave 0..7
    const int oc   = lane & 31;
    const int half = lane >> 5;

    unsigned int*   ldsw = (unsigned int*)lds;
    unsigned short* ldsu = (unsigned short*)lds;
    const float* fb = fmap + (size_t)b * CIN * HW;

    // ---- staging decomposition ----
    const int qlow = t & 7;                   // bits 0..2
    const int P    = (t >> 3) & 15;           // ci-pair, bits 3..6
    const int qhi  = t >> 7;                  // bits 7..8
    const int ci0  = P * 2;
    const int c    = P >> 2;                  // chunk 0..3
    const int o2   = P & 3;                   // dword within 16B slot
    const int qbase = qlow + 8 * qhi;         // 0..31
    const float* planeA = fb + (size_t)ci0 * HW;
    const float* planeB = fb + (size_t)(ci0 + 1) * HW;

    // load of quad-index q (j静态, q = qbase + 32j); j<=4 always valid q<162
    #define STAGE_LOAD(J, VA, VB)                                              \
        {                                                                      \
            const int q  = qbase + 32 * (J);                                   \
            VA = make_float4(0.f, 0.f, 0.f, 0.f);                              \
            VB = make_float4(0.f, 0.f, 0.f, 0.f);                              \
            if ((J) < 5 || q < 162) {                                          \
                const int r  = q / 9;                                          \
                const int qq = q - r * 9;                                      \
                const int gy = y0 + r - 1;                                     \
                const int gx = x0 + qq * 4;                                    \
                if (gy >= 0 && gy < HH && gx < WW) {                           \
                    const size_t off = (size_t)gy * WW + gx;                   \
                    VA = *reinterpret_cast<const float4*>(planeA + off);       \
                    VB = *reinterpret_cast<const float4*>(planeB + off);       \
                }                                                              \
            }                                                                  \
        }

    #define STAGE_WRITE(J, VA, VB)                                             \
        {                                                                      \
            const int q = qbase + 32 * (J);                                    \
            if ((J) < 5 || q < 162) {                                          \
                const int r  = q / 9;                                          \
                const int qq = q - r * 9;                                      \
                const int s0 = r * SPR + 1 + qq * 4;                           \
                const int wbase = (c * CH_STRIDE) * 4;                         \
                ldsw[wbase + swz(s0 + 0) * 4 + o2] = pack2(VA.x, VB.x);        \
                ldsw[wbase + swz(s0 + 1) * 4 + o2] = pack2(VA.y, VB.y);        \
                ldsw[wbase + swz(s0 + 2) * 4 + o2] = pack2(VA.z, VB.z);        \
                ldsw[wbase + swz(s0 + 3) * 4 + o2] = pack2(VA.w, VB.w);        \
            }                                                                  \
        }

    float4 aA, bA, aB, bB;
    STAGE_LOAD(0, aA, bA)
    STAGE_LOAD(1, aB, bB)
    STAGE_WRITE(0, aA, bA)
    STAGE_LOAD(2, aA, bA)
    STAGE_WRITE(1, aB, bB)
    STAGE_LOAD(3, aB, bB)
    STAGE_WRITE(2, aA, bA)
    STAGE_LOAD(4, aA, bA)
    STAGE_WRITE(3, aB, bB)
    STAGE_LOAD(5, aB, bB)
    STAGE_WRITE(4, aA, bA)
    STAGE_WRITE(5, aB, bB)
    #undef STAGE_LOAD
    #undef STAGE_WRITE

    // halo column gx = x0-1 (slot xi=0 per row): 576 = 32ci x 18r entries
    {
        const int ci = t & 31, r = t >> 5;    // r 0..15
        const int gy = y0 + r - 1;
        float f = 0.0f;
        if (gy >= 0 && gy < HH && x0 > 0)
            f = fb[(size_t)ci * HW + (size_t)gy * WW + (x0 - 1)];
        ldsu[((ci >> 3) * CH_STRIDE + swz(r * SPR)) * 8 + (ci & 7)] = to_bf16(f);
    }
    if (t < 64) {
        const int ci = t & 31, r = 16 + (t >> 5);   // r 16,17
        const int gy = y0 + r - 1;
        float f = 0.0f;
        if (gy >= 0 && gy < HH && x0 > 0)
            f = fb[(size_t)ci * HW + (size_t)gy * WW + (x0 - 1)];
        ldsu[((ci >> 3) * CH_STRIDE + swz(r * SPR)) * 8 + (ci & 7)] = to_bf16(f);
    }
    __syncthreads();

    // ---- compute: wave w -> row-tiles w and w+8 ----
    const unsigned short* wp = wtb + (size_t)(b * COUT + oc) * 288 + half * 8;
    const int col = oc;                       // output x within tile

    f32x16 acc0, acc1;
    #pragma unroll
    for (int reg = 0; reg < 16; ++reg) { acc0[reg] = 0.0f; acc1[reg] = 0.0f; }

    __builtin_amdgcn_s_setprio(1);
    #pragma unroll
    for (int s = 0; s < 18; ++s) {
        const int tap = s >> 1;               // 0..8
        const int dy  = tap / 3;
        const int dx  = tap % 3;
        const int cc  = ((s & 1) << 1) | half;   // 16B chunk (8 ci)
        const short8 af = *reinterpret_cast<const short8*>(wp + s * 16);
        const int xi  = col + dx;             // 0..33  (gx = x0+xi-1)
        {
            const int slot = (w + dy) * SPR + xi;
            const short8 bf = lds[cc * CH_STRIDE + swz(slot)];
            acc0 = __builtin_amdgcn_mfma_f32_32x32x16_bf16(af, bf, acc0, 0, 0, 0);
        }
        {
            const int slot = (w + 8 + dy) * SPR + xi;
            const short8 bf = lds[cc * CH_STRIDE + swz(slot)];
            acc1 = __builtin_amdgcn_mfma_f32_32x32x16_bf16(af, bf, acc1, 0, 0, 0);
        }
    }
    __builtin_amdgcn_s_setprio(0);

    // C/D layout (verified m74/m101): col = lane&31, row = (reg&3)+8*(reg>>2)+4*half
    {
        const int gy = y0 + w;
        float* op = out + (size_t)(b * COUT) * HW + (size_t)gy * WW + x0 + col;
        #pragma unroll
        for (int reg = 0; reg < 16; ++reg) {
            const int oc_o = (reg & 3) + 8 * (reg >> 2) + 4 * half;
            __builtin_nontemporal_store(acc0[reg], op + (size_t)oc_o * HW);
        }
    }
    {
        const int gy = y0 + w + 8;
        float* op = out + (size_t)(b * COUT) * HW + (size_t)gy * WW + x0 + col;
        #pragma unroll
        for (int reg = 0; reg < 16; ++reg) {
            const int oc_o = (reg & 3) + 8 * (reg >> 2) + 4 * half;
            __builtin_nontemporal_store(acc1[reg], op + (size_t)oc_o * HW);
        }
    }
}

// ---------------------------------------------------------------------------
extern "C" void kernel_launch(void* const* d_in, const int* in_sizes, int n_in,
                              void* d_out, int out_size, void* d_ws, size_t ws_size,
                              hipStream_t stream) {
    const float* fmap       = (const float*)d_in[0];
    const float* mod        = (const float*)d_in[1];
    const float* kernel_mod = (const float*)d_in[2];
    const float* weights    = (const float*)d_in[3];
    float* out = (float*)d_out;
    unsigned short* wtb = (unsigned short*)d_ws;   // [8][32][288] bf16 = 147,456 B

    prep_weights<<<dim3(BATCH * COUT), dim3(320), 0, stream>>>(
        mod, kernel_mod, weights, wtb);

    conv_fused<<<dim3((WW / XW) * (HH / ROWS) * BATCH), dim3(512), 0, stream>>>(
        fmap, wtb, out);
}

// Round 9
// 153.657 us; speedup vs baseline: 2.9447x; 2.9447x over previous
//
#include <hip/hip_runtime.h>
#include <hip/hip_bf16.h>

#define BATCH 8
#define CIN 32
#define COUT 32
#define NK 4
#define HH 512
#define WW 512
#define HW (HH*WW)
#define EPSV 1e-8f

typedef __attribute__((ext_vector_type(8))) short short8;   // bf16 MFMA frag (4 VGPR)
typedef __attribute__((ext_vector_type(16))) float f32x16;  // 32x32 accumulator
typedef __attribute__((ext_vector_type(4))) float f32x4;    // native vec4 for NT stores

static __device__ __forceinline__ unsigned short to_bf16(float f) {
    __hip_bfloat16 h = __float2bfloat16(f);
    return *reinterpret_cast<unsigned short*>(&h);
}

// ---------------------------------------------------------------------------
// Kernel 1: mixed+modulated+demodulated weights -> bf16 wt[b][oc][k], k=tap*32+ci
// ---------------------------------------------------------------------------
__global__ __launch_bounds__(320) void prep_weights(
    const float* __restrict__ mod,         // [B, CIN]
    const float* __restrict__ kernel_mod,  // [B, NK]
    const float* __restrict__ weights,     // [NK, COUT, CIN, 3, 3]
    unsigned short* __restrict__ wtb)      // [B, COUT, 288] bf16
{
    const int b  = blockIdx.x / COUT;
    const int oc = blockIdx.x % COUT;
    const int t  = threadIdx.x;            // 0..319, active < 288

    const float k0 = kernel_mod[b * NK + 0];
    const float k1 = kernel_mod[b * NK + 1];
    const float k2 = kernel_mod[b * NK + 2];
    const float k3 = kernel_mod[b * NK + 3];
    const float mx = fmaxf(fmaxf(k0, k1), fmaxf(k2, k3));
    const float e0 = expf(k0 - mx), e1 = expf(k1 - mx);
    const float e2 = expf(k2 - mx), e3 = expf(k3 - mx);
    const float inv_s = 1.0f / (e0 + e1 + e2 + e3);
    const float a0 = e0 * inv_s, a1 = e1 * inv_s, a2 = e2 * inv_s, a3 = e3 * inv_s;

    float w = 0.0f;
    int i = 0, tap = 0;
    if (t < CIN * 9) {
        i   = t / 9;
        tap = t % 9;
        const int base = (oc * CIN + i) * 9 + tap;
        const int nstride = COUT * CIN * 9;
        w = a0 * weights[base]
          + a1 * weights[base + nstride]
          + a2 * weights[base + 2 * nstride]
          + a3 * weights[base + 3 * nstride];
        w *= (mod[b * CIN + i] + 1.0f);
    }

    float s = w * w;
    #pragma unroll
    for (int off = 1; off < 64; off <<= 1) s += __shfl_xor(s, off);
    __shared__ float red[5];
    const int wid = t >> 6, lane = t & 63;
    if (lane == 0) red[wid] = s;
    __syncthreads();
    const float tot = red[0] + red[1] + red[2] + red[3] + red[4];
    const float inv_norm = rsqrtf(fmaxf(tot, EPSV));

    if (t < CIN * 9)
        wtb[(b * COUT + oc) * 288 + tap * CIN + i] = to_bf16(w * inv_norm);
}

// ---------------------------------------------------------------------------
// Kernel 2 (fused v5 = proven v2 staging + swapped-operand epilogue).
// Block: 512 thr (8 waves), tile 16 rows x 32 px, one batch slice.
// Staging (v2, 114us-proven): lane-pair float4 loads (2x512B dense segments
// per instr), direct 2B scatter into interleaved LDS [chunk(8ci)][slot][16B],
// quad-local swizzle. Slots 0..35 = gx x0..x0+35; slot 36 = left halo x0-1.
// Compute: wave w -> row-tiles (w, w+8); 18 x mfma per tile with operands
// SWAPPED: D[m=px][n=oc] (A/B per-lane layouts are symmetric, both lane&31 +
// k=half*8+j, as proven by v2 using the same construction for both operands).
// Epilogue: reg&3 = consecutive x -> 4 contiguous float4 stores per acc.
// ---------------------------------------------------------------------------
#define ROWS 16
#define XW 32
#define SR 18              // staged rows
#define SPR 37             // slots per row: 36 quad px + 1 left-halo
#define CH_STRIDE 668      // padded chunk stride (swizzle image <= 667)
#define QP 176             // padded quads per ci (162 real = 18 rows x 9)

static __device__ __forceinline__ int swz(int s) {
    return (s & ~3) | ((s ^ (s >> 2)) & 3);   // involution within quad groups
}

__global__ __launch_bounds__(512, 6) void conv_fused(
    const float* __restrict__ fmap,           // [B, CIN, H, W] f32
    const unsigned short* __restrict__ wtb,   // [B, COUT, 288] bf16
    float* __restrict__ out)                  // [B, COUT, H, W] f32
{
    __shared__ short8 lds[4 * CH_STRIDE];     // 42,752 B -> 3 blocks/CU

    // XCD-pinned decomposition: XCD (n&7) owns batch b, sweeps tiles row-major
    const int n  = blockIdx.x;
    const int b  = n & 7;
    const int m  = n >> 3;
    const int x0 = (m & 15) * XW;             // 16 x-tiles
    const int y0 = (m >> 4) * ROWS;           // 32 y-tiles

    const int t    = threadIdx.x;
    const int lane = t & 63;
    const int w    = t >> 6;                  // wave 0..7
    const int oc   = lane & 31;
    const int half = lane >> 5;

    unsigned short* ldsu = (unsigned short*)lds;
    const float* fb = fmap + (size_t)b * CIN * HW;

    // ---- P1: dense quad staging (32 ci x 162 quads)  [v2 verbatim] ----
    #pragma unroll
    for (int k = 0; k < 11; ++k) {
        const int u  = t + 512 * k;           // < 5632 = 32*QP, no guard needed
        const int pr = u >> 1;                // lane-pair id
        const int cp = pr / QP;               // ci-pair 0..15
        const int q  = pr - cp * QP;          // 0..175
        const int ci = cp * 2 + (u & 1);
        if (q < 162) {
            const int r  = q / 9;             // 0..17
            const int qq = q - r * 9;         // 0..8
            const int gy = y0 + r - 1;
            const int gx = x0 + qq * 4;       // 16B-aligned (x0 % 32 == 0)
            float4 v = make_float4(0.f, 0.f, 0.f, 0.f);
            if (gy >= 0 && gy < HH && gx + 3 < WW)
                v = *reinterpret_cast<const float4*>(
                        fb + (size_t)ci * HW + (size_t)gy * WW + gx);
            const int c = ci >> 3, o = ci & 7;
            const int s0 = r * SPR + qq * 4;
            ldsu[(c * CH_STRIDE + swz(s0 + 0)) * 8 + o] = to_bf16(v.x);
            ldsu[(c * CH_STRIDE + swz(s0 + 1)) * 8 + o] = to_bf16(v.y);
            ldsu[(c * CH_STRIDE + swz(s0 + 2)) * 8 + o] = to_bf16(v.z);
            ldsu[(c * CH_STRIDE + swz(s0 + 3)) * 8 + o] = to_bf16(v.w);
        }
    }
    // ---- P1b: left halo column (gx = x0-1) -> slot 36 per row ----
    #pragma unroll
    for (int k = 0; k < 2; ++k) {
        const int e = t + 512 * k;
        if (e < 576) {                        // 32 ci x 18 rows
            const int ci = e & 31;
            const int r  = e >> 5;
            const int gy = y0 + r - 1;
            float f = 0.0f;
            if (gy >= 0 && gy < HH && x0 > 0)
                f = fb[(size_t)ci * HW + (size_t)gy * WW + (x0 - 1)];
            const int c = ci >> 3, o = ci & 7;
            ldsu[(c * CH_STRIDE + swz(r * SPR + 36)) * 8 + o] = to_bf16(f);
        }
    }
    __syncthreads();

    // ---- compute: wave w -> row-tiles w and w+8 (swapped operands) ----
    const unsigned short* wp = wtb + (size_t)(b * COUT + oc) * 288 + half * 8;
    const int col = oc;                       // px index within tile (lane&31)

    f32x16 acc0, acc1;
    #pragma unroll
    for (int reg = 0; reg < 16; ++reg) { acc0[reg] = 0.0f; acc1[reg] = 0.0f; }

    #pragma unroll
    for (int s = 0; s < 18; ++s) {
        const int tap = s >> 1;               // 0..8
        const int dy  = tap / 3;
        const int dx  = tap % 3;
        const int c   = ((s & 1) << 1) | half;   // 16B chunk (8 ci)
        const short8 af = *reinterpret_cast<const short8*>(wp + s * 16);
        const int xcd = col + dx;
        const int xx  = (xcd == 0) ? 36 : (xcd - 1);   // left halo remap
        {
            const int slot = (w + dy) * SPR + xx;
            const short8 bf = lds[c * CH_STRIDE + swz(slot)];
            acc0 = __builtin_amdgcn_mfma_f32_32x32x16_bf16(bf, af, acc0, 0, 0, 0);
        }
        {
            const int slot = (w + 8 + dy) * SPR + xx;
            const short8 bf = lds[c * CH_STRIDE + swz(slot)];
            acc1 = __builtin_amdgcn_mfma_f32_32x32x16_bf16(bf, af, acc1, 0, 0, 0);
        }
    }

    // D[m=px][n=oc]: lane holds oc = lane&31; px = (reg&3) + 8*(reg>>2) + 4*half
    // -> reg groups of 4 give consecutive x: contiguous float4 stores.
    {
        const int gy = y0 + w;
        float* op = out + (size_t)(b * COUT + oc) * HW + (size_t)gy * WW + x0;
        #pragma unroll
        for (int g = 0; g < 4; ++g) {
            f32x4 v = { acc0[4*g+0], acc0[4*g+1], acc0[4*g+2], acc0[4*g+3] };
            __builtin_nontemporal_store(v,
                reinterpret_cast<f32x4*>(op + 8 * g + 4 * half));
        }
    }
    {
        const int gy = y0 + w + 8;
        float* op = out + (size_t)(b * COUT + oc) * HW + (size_t)gy * WW + x0;
        #pragma unroll
        for (int g = 0; g < 4; ++g) {
            f32x4 v = { acc1[4*g+0], acc1[4*g+1], acc1[4*g+2], acc1[4*g+3] };
            __builtin_nontemporal_store(v,
                reinterpret_cast<f32x4*>(op + 8 * g + 4 * half));
        }
    }
}

// ---------------------------------------------------------------------------
extern "C" void kernel_launch(void* const* d_in, const int* in_sizes, int n_in,
                              void* d_out, int out_size, void* d_ws, size_t ws_size,
                              hipStream_t stream) {
    const float* fmap       = (const float*)d_in[0];
    const float* mod        = (const float*)d_in[1];
    const float* kernel_mod = (const float*)d_in[2];
    const float* weights    = (const float*)d_in[3];
    float* out = (float*)d_out;
    unsigned short* wtb = (unsigned short*)d_ws;   // [8][32][288] bf16 = 147,456 B

    prep_weights<<<dim3(BATCH * COUT), dim3(320), 0, stream>>>(
        mod, kernel_mod, weights, wtb);

    conv_fused<<<dim3((WW / XW) * (HH / ROWS) * BATCH), dim3(512), 0, stream>>>(
        fmap, wtb, out);
}